// Round 4
// baseline (175.907 us; speedup 1.0000x reference)
//
#include <hip/hip_runtime.h>
#include <cstdint>

// HashEmbedder: 16-level hash-grid encoding, IN_DIM=3, F=2.
// Levels 0..5 dense (res 16,22,30,42,58,80), levels 6..15 hashed (T=524309).
//
// R4 structure:
//  - cost-weighted contiguous XCD schedule: level order [6..15,5,4,3,2,1,0],
//    per-chunk costs {hashed:10, l5:6, l4:5, l0-3:2}, 8 equal-cost spans
//    (each XCD walks its span in dispatch order -> <=2 tables L2-hot).
//  - hashed gathers via agent-scope relaxed atomic loads (sc0): bypass the
//    32KB L1 (0.8% hit rate on 4.2MB tables), still allocate in L2.
//  - z-corner pairing (weights use dims 0,1 only -- reference quirk):
//    dense = one 16B load per xy-corner; hashed = w*(v0+v1).
//  - ws[level][n] staging + LDS-transposed float4-coalesced epilogue.

namespace {
constexpr int NLEV   = 16;
constexpr int SDENSE = 6;
constexpr uint64_t T_HASH = 524309ull;

typedef float f2v __attribute__((ext_vector_type(2)));
typedef float f4v __attribute__((ext_vector_type(4)));
struct __attribute__((packed, aligned(8))) F4A8 { f4v v; };  // 16B load, align 8
static_assert(sizeof(F4A8) == 16, "");

__constant__ int c_res[NLEV] = {16,22,30,42,58,80,110,152,210,290,400,553,763,1053,1453,2005};
// ENTRIES_SIZE = float32(double(1)/(n-1)) -- replicate the double->float cast exactly
__constant__ float c_es[NLEV] = {
    (float)(1.0/15.0),  (float)(1.0/21.0),  (float)(1.0/29.0),  (float)(1.0/41.0),
    (float)(1.0/57.0),  (float)(1.0/79.0),  (float)(1.0/109.0), (float)(1.0/151.0),
    (float)(1.0/209.0), (float)(1.0/289.0), (float)(1.0/399.0), (float)(1.0/552.0),
    (float)(1.0/762.0), (float)(1.0/1052.0),(float)(1.0/1452.0),(float)(1.0/2004.0)
};
__constant__ int c_base[SDENSE] = {0, 4096, 14744, 41744, 115832, 310944};

// processing order (hashed first, then l5,l4, then small dense) and the
// 8 equal-cost span cuts (in chunks of 256 points; 512 chunks/level)
__constant__ int c_order[NLEV] = {6,7,8,9,10,11,12,13,14,15,5,4,3,2,1,0};
__constant__ int c_cut[9] = {0, 762, 1523, 2285, 3046, 3808, 4570, 5472, 8192};
} // namespace

// sc0 (agent-coherent) 8B load: bypasses L1, allocates in L2
__device__ __forceinline__ f2v ld_l2_f2(const float2* p) {
    unsigned long long u = __hip_atomic_load(
        (const unsigned long long*)p, __ATOMIC_RELAXED, __HIP_MEMORY_SCOPE_AGENT);
    union { unsigned long long u; f2v f; } cv; cv.u = u;
    return cv.f;
}

// ---- per-(point,level) math with z-corner pairing ----------------------
__device__ __forceinline__ void level_eval(
    const float2* __restrict__ dense,
    const float2* __restrict__ hashtab,
    float x0, float x1, float x2, int l,
    float& acc0, float& acc1)
{
    int   res = c_res[l];
    float es  = c_es[l];
    // flt = x / ENTRIES_SIZE (float32 IEEE division, matches numpy)
    float f0 = x0 / es;
    float f1 = x1 / es;
    float f2 = x2 / es;
    int nm1 = res - 1;

    // per-corner coords: trunc(flt + offset) then clip -- offset added in f32
    // BEFORE truncation (binade-crossing rounding must match the reference)
    int i00 = min(max((int)f0, 0), nm1);
    int i01 = min(max((int)f1, 0), nm1);
    int i02 = min(max((int)f2, 0), nm1);
    int i10 = min(max((int)(f0 + 1.0f), 0), nm1);
    int i11 = min(max((int)(f1 + 1.0f), 0), nm1);

    float off0 = f0 - (float)i00;
    float off1 = f1 - (float)i01;
    // reference multiplies lerp weights over dims 0 and 1 ONLY (replicated):
    // corners differing only in dim2 share a weight -> pair them.
    float w0a = 1.0f - off0, w0b = off0;
    float w1a = 1.0f - off1, w1b = off1;
    float wxy0 = w0a * w1a, wxy1 = w0a * w1b, wxy2 = w0b * w1a, wxy3 = w0b * w1b;

    acc0 = 0.0f; acc1 = 0.0f;

    if (l < SDENSE) {
        int s0   = res * res;
        int base = c_base[l];
        int A0 = i00 * s0,  A1 = i10 * s0;
        int B0 = i01 * res, B1 = i11 * res;
        // z-pair: i12 == zlo+1 always; corner i02 is .xy if i02==zlo else .zw
        int  zlo    = min(i02, nm1 - 1);
        bool lowSel = (i02 == zlo);
        #pragma unroll
        for (int k = 0; k < 4; ++k) {
            int idx = ((k & 2) ? A1 : A0) + ((k & 1) ? B1 : B0) + zlo + base;
            f4v v = reinterpret_cast<const F4A8*>(dense + idx)->v;  // dwordx4 @8B
            float lo0 = lowSel ? v.x : v.z;
            float lo1 = lowSel ? v.y : v.w;
            float w = (k & 2) ? ((k & 1) ? wxy3 : wxy2) : ((k & 1) ? wxy1 : wxy0);
            acc0 += w * (lo0 + v.z);
            acc1 += w * (lo1 + v.w);
        }
    } else {
        // products up to 2005*83492791 ~= 2^38 -> 64-bit before XOR/mod
        uint64_t a0 = (uint64_t)(uint32_t)i00;
        uint64_t a1 = (uint64_t)(uint32_t)i10;
        uint64_t b0 = (uint64_t)(uint32_t)i01 * 19349663ull;
        uint64_t b1 = (uint64_t)(uint32_t)i11 * 19349663ull;
        uint64_t cz0 = (uint64_t)(uint32_t)i02 * 83492791ull;
        uint64_t cz1 = (uint64_t)(uint32_t)min(i02 + 1, nm1) * 83492791ull;
        uint32_t rowbase = (uint32_t)(l - SDENSE) * (uint32_t)T_HASH;
        #pragma unroll
        for (int k = 0; k < 4; ++k) {
            uint64_t hb = 1ull ^ ((k & 2) ? a1 : a0) ^ ((k & 1) ? b1 : b0);
            uint32_t idx0 = rowbase + (uint32_t)((hb ^ cz0) % T_HASH);
            uint32_t idx1 = rowbase + (uint32_t)((hb ^ cz1) % T_HASH);
            f2v v0 = ld_l2_f2(hashtab + idx0);   // sc0: skip L1, hit L2
            f2v v1 = ld_l2_f2(hashtab + idx1);
            float w = (k & 2) ? ((k & 1) ? wxy3 : wxy2) : ((k & 1) ? wxy1 : wxy0);
            acc0 += w * (v0.x + v1.x);
            acc1 += w * (v0.y + v1.y);
        }
    }
}

// ---- R4 fast path: cost-balanced contiguous XCD spans ------------------
// Requires npts == 131072 (512 chunks of 256 points per level).
// x = blockIdx&7 (~XCD), s = blockIdx>>3 in [0,1024): slot s of XCD x
// processes ordered-chunk ids [lo + s*L/1024, lo + (s+1)*L/1024), L=span len.
// Slots ascend with dispatch order -> each XCD walks its levels sequentially.
__global__ __launch_bounds__(256) void hashgrid_level(
    const float*  __restrict__ xyz,
    const float2* __restrict__ dense,
    const float2* __restrict__ hashtab,
    float2*       __restrict__ ws,
    int npts)
{
    int b = blockIdx.x;
    int x = b & 7;
    int s = b >> 3;
    int lo = c_cut[x];
    int L  = c_cut[x + 1] - lo;
    int c0 = lo + ((s * L) >> 10);
    int c1 = lo + (((s + 1) * L) >> 10);
    int t  = threadIdx.x;

    __shared__ float sxyz[768];

    for (int c = c0; c < c1; ++c) {
        int level = c_order[c >> 9];
        int n0    = (c & 511) << 8;

        __syncthreads();   // protect sxyz reuse across chunk iterations
        sxyz[t      ] = xyz[3 * n0 + t      ];
        sxyz[t + 256] = xyz[3 * n0 + t + 256];
        sxyz[t + 512] = xyz[3 * n0 + t + 512];
        __syncthreads();
        float x0 = sxyz[3 * t], x1 = sxyz[3 * t + 1], x2 = sxyz[3 * t + 2];

        float acc0, acc1;
        level_eval(dense, hashtab, x0, x1, x2, level, acc0, acc1);

        f2v val = {acc0, acc1};
        __builtin_nontemporal_store(val, (f2v*)(ws + (size_t)level * npts + n0 + t));
    }
}

// ---- epilogue: ws[level][n] -> out[n][35], LDS transpose, float4 stores -
__global__ __launch_bounds__(256) void gather_out(
    const float*  __restrict__ xyz,
    const float2* __restrict__ ws,
    float*        __restrict__ out,
    int npts)
{
    __shared__ __align__(16) float tile[256 * 35];   // 35840 B
    int t  = threadIdx.x;
    int n0 = blockIdx.x << 8;
    int n  = n0 + t;

    // xyz passthrough: coalesced read, scatter into tile (pt = pos/3)
    #pragma unroll
    for (int j = 0; j < 3; ++j) {
        int pos = t + (j << 8);
        float v = xyz[3 * n0 + pos];
        int pt = pos / 3, dim = pos - 3 * pt;
        tile[pt * 35 + dim] = v;
    }
    // level features: coalesced nt float2 loads; stride-35 LDS writes (2-way, free)
    #pragma unroll
    for (int l = 0; l < NLEV; ++l) {
        f2v v = __builtin_nontemporal_load((const f2v*)(ws + (size_t)l * npts + n));
        tile[t * 35 + 3 + 2 * l] = v.x;
        tile[t * 35 + 4 + 2 * l] = v.y;
    }
    __syncthreads();

    // 256*35 floats = 2240 float4, fully coalesced nt stores
    const f4v* src = (const f4v*)tile;
    f4v* dst = (f4v*)(out + (size_t)n0 * 35);
    #pragma unroll
    for (int i = 0; i < 9; ++i) {
        int idx = t + (i << 8);
        if (idx < 2240) __builtin_nontemporal_store(src[idx], dst + idx);
    }
}

// ---- fallback: monolithic kernel (any npts, no workspace) --------------
__global__ __launch_bounds__(256) void hashgrid_mono(
    const float*  __restrict__ xyz,
    const float2* __restrict__ dense,
    const float2* __restrict__ hashtab,
    float*        __restrict__ out,
    int npts)
{
    int tid = blockIdx.x * 256 + threadIdx.x;
    int l = tid & (NLEV - 1);
    int n = tid >> 4;
    if (n >= npts) return;

    float x0 = xyz[3*n+0], x1 = xyz[3*n+1], x2 = xyz[3*n+2];
    float acc0, acc1;
    level_eval(dense, hashtab, x0, x1, x2, l, acc0, acc1);

    float* o = out + (size_t)n * 35;
    if (l == 0) { o[0] = x0; o[1] = x1; o[2] = x2; }
    o[3 + 2*l] = acc0;
    o[4 + 2*l] = acc1;
}

extern "C" void kernel_launch(void* const* d_in, const int* in_sizes, int n_in,
                              void* d_out, int out_size, void* d_ws, size_t ws_size,
                              hipStream_t stream) {
    const float*  xyz     = (const float*)d_in[0];
    const float2* dense   = (const float2*)d_in[1];
    const float2* hashtab = (const float2*)d_in[2];
    float* out = (float*)d_out;

    int npts = in_sizes[0] / 3;   // 131072 expected
    size_t ws_need = (size_t)NLEV * (size_t)npts * sizeof(float2);

    if (npts == 131072 && ws_size >= ws_need) {
        float2* ws = (float2*)d_ws;
        hashgrid_level<<<8192, 256, 0, stream>>>(xyz, dense, hashtab, ws, npts);
        gather_out<<<npts / 256, 256, 0, stream>>>(xyz, ws, out, npts);
    } else {
        int total  = npts * NLEV;
        int blocks = (total + 255) / 256;
        hashgrid_mono<<<blocks, 256, 0, stream>>>(xyz, dense, hashtab, out, npts);
    }
}

// Round 5
// 155.404 us; speedup vs baseline: 1.1319x; 1.1319x over previous
//
#include <hip/hip_runtime.h>
#include <cstdint>

// HashEmbedder: 16-level hash-grid encoding, IN_DIM=3, F=2.
// Levels 0..5 dense (res 16,22,30,42,58,80), levels 6..15 hashed (T=524309).
//
// R5 = R3 structure (79us main kernel) + ONE change: flat cost-balanced
// XCD schedule. Level order [6..15,5,4,3,2,1,0]; per-chunk unit costs
// {hashed:8, l5..l2:4, l1:3, l0:1} (= expected L1-missing line requests per
// point); cuts at equal cumulative cost (6400 units/XCD). One chunk per
// block (no loops, single barrier pair); grid 8*2112 so the largest span
// maps 1:1 and excess blocks exit immediately. sc0 atomic loads REVERTED
// (R4 post-mortem: regression).

namespace {
constexpr int NLEV   = 16;
constexpr int SDENSE = 6;
constexpr uint64_t T_HASH = 524309ull;

typedef float f2v __attribute__((ext_vector_type(2)));
typedef float f4v __attribute__((ext_vector_type(4)));
struct __attribute__((packed, aligned(8))) F4A8 { f4v v; };  // 16B load, align 8
static_assert(sizeof(F4A8) == 16, "");

__constant__ int c_res[NLEV] = {16,22,30,42,58,80,110,152,210,290,400,553,763,1053,1453,2005};
// ENTRIES_SIZE = float32(double(1)/(n-1)) -- replicate the double->float cast exactly
__constant__ float c_es[NLEV] = {
    (float)(1.0/15.0),  (float)(1.0/21.0),  (float)(1.0/29.0),  (float)(1.0/41.0),
    (float)(1.0/57.0),  (float)(1.0/79.0),  (float)(1.0/109.0), (float)(1.0/151.0),
    (float)(1.0/209.0), (float)(1.0/289.0), (float)(1.0/399.0), (float)(1.0/552.0),
    (float)(1.0/762.0), (float)(1.0/1052.0),(float)(1.0/1452.0),(float)(1.0/2004.0)
};
__constant__ int c_base[SDENSE] = {0, 4096, 14744, 41744, 115832, 310944};

// processing order (hashed first, then dense large->small) and the 8
// equal-cost span cuts (in ordered-chunk ids; 512 chunks of 256 pts/level)
__constant__ int c_order[NLEV] = {6,7,8,9,10,11,12,13,14,15,5,4,3,2,1,0};
__constant__ int c_cut[9] = {0, 800, 1600, 2400, 3200, 4000, 4800, 6080, 8192};
constexpr int SLOTS_PER_XCD = 2112;   // = max span (XCD7); grid = 8*2112
} // namespace

// ---- per-(point,level) math with z-corner pairing ----------------------
__device__ __forceinline__ void level_eval(
    const float2* __restrict__ dense,
    const float2* __restrict__ hashtab,
    float x0, float x1, float x2, int l,
    float& acc0, float& acc1)
{
    int   res = c_res[l];
    float es  = c_es[l];
    // flt = x / ENTRIES_SIZE (float32 IEEE division, matches numpy)
    float f0 = x0 / es;
    float f1 = x1 / es;
    float f2 = x2 / es;
    int nm1 = res - 1;

    // per-corner coords: trunc(flt + offset) then clip -- offset added in f32
    // BEFORE truncation (binade-crossing rounding must match the reference)
    int i00 = min(max((int)f0, 0), nm1);
    int i01 = min(max((int)f1, 0), nm1);
    int i02 = min(max((int)f2, 0), nm1);
    int i10 = min(max((int)(f0 + 1.0f), 0), nm1);
    int i11 = min(max((int)(f1 + 1.0f), 0), nm1);

    float off0 = f0 - (float)i00;
    float off1 = f1 - (float)i01;
    // reference multiplies lerp weights over dims 0 and 1 ONLY (replicated):
    // corners differing only in dim2 share a weight -> pair them.
    float w0a = 1.0f - off0, w0b = off0;
    float w1a = 1.0f - off1, w1b = off1;
    float wxy0 = w0a * w1a, wxy1 = w0a * w1b, wxy2 = w0b * w1a, wxy3 = w0b * w1b;

    acc0 = 0.0f; acc1 = 0.0f;

    if (l < SDENSE) {
        int s0   = res * res;
        int base = c_base[l];
        int A0 = i00 * s0,  A1 = i10 * s0;
        int B0 = i01 * res, B1 = i11 * res;
        // z-pair: i12 == zlo+1 always; corner i02 is .xy if i02==zlo else .zw
        int  zlo    = min(i02, nm1 - 1);
        bool lowSel = (i02 == zlo);
        #pragma unroll
        for (int k = 0; k < 4; ++k) {
            int idx = ((k & 2) ? A1 : A0) + ((k & 1) ? B1 : B0) + zlo + base;
            f4v v = reinterpret_cast<const F4A8*>(dense + idx)->v;  // dwordx4 @8B
            float lo0 = lowSel ? v.x : v.z;
            float lo1 = lowSel ? v.y : v.w;
            float w = (k & 2) ? ((k & 1) ? wxy3 : wxy2) : ((k & 1) ? wxy1 : wxy0);
            acc0 += w * (lo0 + v.z);
            acc1 += w * (lo1 + v.w);
        }
    } else {
        // products up to 2005*83492791 ~= 2^38 -> 64-bit before XOR/mod
        uint64_t a0 = (uint64_t)(uint32_t)i00;
        uint64_t a1 = (uint64_t)(uint32_t)i10;
        uint64_t b0 = (uint64_t)(uint32_t)i01 * 19349663ull;
        uint64_t b1 = (uint64_t)(uint32_t)i11 * 19349663ull;
        uint64_t cz0 = (uint64_t)(uint32_t)i02 * 83492791ull;
        uint64_t cz1 = (uint64_t)(uint32_t)min(i02 + 1, nm1) * 83492791ull;
        uint32_t rowbase = (uint32_t)(l - SDENSE) * (uint32_t)T_HASH;
        #pragma unroll
        for (int k = 0; k < 4; ++k) {
            uint64_t hb = 1ull ^ ((k & 2) ? a1 : a0) ^ ((k & 1) ? b1 : b0);
            uint32_t idx0 = rowbase + (uint32_t)((hb ^ cz0) % T_HASH);
            uint32_t idx1 = rowbase + (uint32_t)((hb ^ cz1) % T_HASH);
            float2 v0 = hashtab[idx0];
            float2 v1 = hashtab[idx1];
            float w = (k & 2) ? ((k & 1) ? wxy3 : wxy2) : ((k & 1) ? wxy1 : wxy0);
            acc0 += w * (v0.x + v1.x);
            acc1 += w * (v0.y + v1.y);
        }
    }
}

// ---- R5 fast path: flat cost-balanced XCD spans, 1 chunk/block ---------
// Requires npts == 131072 (512 chunks of 256 points per level).
// x = blockIdx&7 (~XCD), s = blockIdx>>3: chunk = c_cut[x]+s (exit if past
// span end). Slots ascend with dispatch order -> each XCD walks its span's
// levels sequentially, keeping <=2 tables L2-hot.
__global__ __launch_bounds__(256) void hashgrid_level(
    const float*  __restrict__ xyz,
    const float2* __restrict__ dense,
    const float2* __restrict__ hashtab,
    float2*       __restrict__ ws,
    int npts)
{
    int b = blockIdx.x;
    int x = b & 7;
    int s = b >> 3;
    int c = c_cut[x] + s;
    if (c >= c_cut[x + 1]) return;   // excess slot on a light XCD

    int level = c_order[c >> 9];
    int n0    = (c & 511) << 8;
    int t     = threadIdx.x;

    __shared__ float sxyz[768];
    sxyz[t      ] = xyz[3 * n0 + t      ];
    sxyz[t + 256] = xyz[3 * n0 + t + 256];
    sxyz[t + 512] = xyz[3 * n0 + t + 512];
    __syncthreads();
    float x0 = sxyz[3 * t], x1 = sxyz[3 * t + 1], x2 = sxyz[3 * t + 2];

    float acc0, acc1;
    level_eval(dense, hashtab, x0, x1, x2, level, acc0, acc1);

    f2v val = {acc0, acc1};
    __builtin_nontemporal_store(val, (f2v*)(ws + (size_t)level * npts + n0 + t));
}

// ---- epilogue: ws[level][n] -> out[n][35], LDS transpose, float4 stores -
__global__ __launch_bounds__(256) void gather_out(
    const float*  __restrict__ xyz,
    const float2* __restrict__ ws,
    float*        __restrict__ out,
    int npts)
{
    __shared__ __align__(16) float tile[256 * 35];   // 35840 B
    int t  = threadIdx.x;
    int n0 = blockIdx.x << 8;
    int n  = n0 + t;

    // xyz passthrough: coalesced read, scatter into tile (pt = pos/3)
    #pragma unroll
    for (int j = 0; j < 3; ++j) {
        int pos = t + (j << 8);
        float v = xyz[3 * n0 + pos];
        int pt = pos / 3, dim = pos - 3 * pt;
        tile[pt * 35 + dim] = v;
    }
    // level features: coalesced nt float2 loads; stride-35 LDS writes (2-way, free)
    #pragma unroll
    for (int l = 0; l < NLEV; ++l) {
        f2v v = __builtin_nontemporal_load((const f2v*)(ws + (size_t)l * npts + n));
        tile[t * 35 + 3 + 2 * l] = v.x;
        tile[t * 35 + 4 + 2 * l] = v.y;
    }
    __syncthreads();

    // 256*35 floats = 2240 float4, fully coalesced nt stores
    const f4v* src = (const f4v*)tile;
    f4v* dst = (f4v*)(out + (size_t)n0 * 35);
    #pragma unroll
    for (int i = 0; i < 9; ++i) {
        int idx = t + (i << 8);
        if (idx < 2240) __builtin_nontemporal_store(src[idx], dst + idx);
    }
}

// ---- fallback: monolithic kernel (any npts, no workspace) --------------
__global__ __launch_bounds__(256) void hashgrid_mono(
    const float*  __restrict__ xyz,
    const float2* __restrict__ dense,
    const float2* __restrict__ hashtab,
    float*        __restrict__ out,
    int npts)
{
    int tid = blockIdx.x * 256 + threadIdx.x;
    int l = tid & (NLEV - 1);
    int n = tid >> 4;
    if (n >= npts) return;

    float x0 = xyz[3*n+0], x1 = xyz[3*n+1], x2 = xyz[3*n+2];
    float acc0, acc1;
    level_eval(dense, hashtab, x0, x1, x2, l, acc0, acc1);

    float* o = out + (size_t)n * 35;
    if (l == 0) { o[0] = x0; o[1] = x1; o[2] = x2; }
    o[3 + 2*l] = acc0;
    o[4 + 2*l] = acc1;
}

extern "C" void kernel_launch(void* const* d_in, const int* in_sizes, int n_in,
                              void* d_out, int out_size, void* d_ws, size_t ws_size,
                              hipStream_t stream) {
    const float*  xyz     = (const float*)d_in[0];
    const float2* dense   = (const float2*)d_in[1];
    const float2* hashtab = (const float2*)d_in[2];
    float* out = (float*)d_out;

    int npts = in_sizes[0] / 3;   // 131072 expected
    size_t ws_need = (size_t)NLEV * (size_t)npts * sizeof(float2);

    if (npts == 131072 && ws_size >= ws_need) {
        float2* ws = (float2*)d_ws;
        hashgrid_level<<<8 * SLOTS_PER_XCD, 256, 0, stream>>>(xyz, dense, hashtab, ws, npts);
        gather_out<<<npts / 256, 256, 0, stream>>>(xyz, ws, out, npts);
    } else {
        int total  = npts * NLEV;
        int blocks = (total + 255) / 256;
        hashgrid_mono<<<blocks, 256, 0, stream>>>(xyz, dense, hashtab, out, npts);
    }
}